// Round 5
// baseline (161.843 us; speedup 1.0000x reference)
//
#include <hip/hip_runtime.h>
#include <cmath>

// Conductance-based LIF scan: T=512 steps, N=65536 neurons.
// R4b: 2 neurons per lane -> dwordx2 loads/stores (512B/instr/wave), 512
// waves = 2 waves/CU. Memory-pipe limited at ~5.1KB per CU per step
// (658MB total through L1/L2); wider vmem ops raise sustained per-CU BW.
// Register double-buffered prefetch of PFD=8 steps hides HBM latency.
// Uses clang ext_vector f32x2 (HIP float2 is a class type that
// __builtin_nontemporal_store rejects).
//
// Numerics identical to passing R1-R3: __f{mul,add,sub}_rn blocks FMA
// contraction, __fdiv_rn, f32 expf. gA == 0 (ADAPT_INC==0), elided.

#ifndef PFD
#define PFD 8   // prefetch depth (steps per register block)
#endif

typedef float f32x2 __attribute__((ext_vector_type(2)));

__global__ __launch_bounds__(128, 1) void lif_scan(
    const float* __restrict__ g_exc,
    const float* __restrict__ g_inh,
    const float* __restrict__ noise,
    const float* __restrict__ v_th,
    const float* __restrict__ tau_ref,
    float* __restrict__ out_spk,   // d_out[0 .. T*N)
    float* __restrict__ out_mem,   // d_out[T*N .. 2*T*N)
    int N, int T,
    float cGE, float cGI, float cALPHA, float cSIGMA)
{
    const int tid = blockIdx.x * blockDim.x + threadIdx.x;  // pair index
    const int N2 = N >> 1;
    if (tid >= N2) return;

    const f32x2* __restrict__ pge = reinterpret_cast<const f32x2*>(g_exc) + tid;
    const f32x2* __restrict__ pgi = reinterpret_cast<const f32x2*>(g_inh) + tid;
    const f32x2* __restrict__ pz  = reinterpret_cast<const f32x2*>(noise) + tid;
    f32x2* __restrict__ pspk = reinterpret_cast<f32x2*>(out_spk) + tid;
    f32x2* __restrict__ pmem = reinterpret_cast<f32x2*>(out_mem) + tid;

    const f32x2 vth2 = reinterpret_cast<const f32x2*>(v_th)[tid];
    const f32x2 trf2 = reinterpret_cast<const f32x2*>(tau_ref)[tid];

    float v0 = 0.f, gE0 = 0.f, gI0 = 0.f, ref0 = 0.f, ou0 = 0.f;
    float v1 = 0.f, gE1 = 0.f, gI1 = 0.f, ref1 = 0.f, ou1 = 0.f;

    // one neuron update; arithmetic order identical to R1-R3 kernels
    auto one = [&](float& v, float& gE, float& gI, float& ref, float& ou,
                   float ge_in, float gi_in, float z,
                   float vth, float trf) -> float {
        gE = __fadd_rn(__fmul_rn(gE, cGE), ge_in);
        gI = __fadd_rn(__fmul_rn(gI, cGI), gi_in);

        const float gt  = __fadd_rn(__fadd_rn(1.0f, gE), gI);
        const float num = __fadd_rn(__fmul_rn(gE, 3.0f), __fmul_rn(gI, -0.5f));
        const float vinf = __fdiv_rn(num, gt);

        const float darg = __fmul_rn(-0.05f, gt);
        const float decay = expf(darg);

        v = __fadd_rn(vinf, __fmul_rn(__fsub_rn(v, vinf), decay));

        ou = __fadd_rn(__fmul_rn(ou, cALPHA), __fmul_rn(cSIGMA, z));
        v = __fadd_rn(v, ou);

        const bool in_ref = (ref > 0.0f);
        if (in_ref) v = 0.0f;

        const bool spike = (v >= vth) && (!in_ref);
        if (spike) v = 0.0f;
        ref = spike ? trf : fmaxf(__fsub_rn(ref, 1.0f), 0.0f);
        return spike ? 1.0f : 0.0f;
    };

    auto step = [&](f32x2 ge_in, f32x2 gi_in, f32x2 z, int tt) {
        f32x2 spk, vm;
        spk.x = one(v0, gE0, gI0, ref0, ou0, ge_in.x, gi_in.x, z.x, vth2.x, trf2.x);
        vm.x = v0;
        spk.y = one(v1, gE1, gI1, ref1, ou1, ge_in.y, gi_in.y, z.y, vth2.y, trf2.y);
        vm.y = v1;
        const size_t off = (size_t)tt * (size_t)N2;
        __builtin_nontemporal_store(spk, pspk + off);
        __builtin_nontemporal_store(vm,  pmem + off);
    };

    f32x2 Age[PFD], Agi[PFD], Az[PFD];
    f32x2 Bge[PFD], Bgi[PFD], Bz[PFD];

    // prime buffer A with steps 0..PFD-1
    #pragma unroll
    for (int i = 0; i < PFD; ++i) {
        const size_t off = (size_t)i * (size_t)N2;
        Age[i] = pge[off]; Agi[i] = pgi[off]; Az[i] = pz[off];
    }

    // main loop: 2*PFD steps per iteration, ping-pong A/B register blocks
    // (T=512 is an exact multiple of 2*PFD=16; clamp is belt-and-braces)
    for (int t = 0; t < T; t += 2 * PFD) {
        #pragma unroll
        for (int i = 0; i < PFD; ++i) {
            int tp = t + PFD + i; tp = tp < T ? tp : T - 1;
            const size_t off = (size_t)tp * (size_t)N2;
            Bge[i] = pge[off]; Bgi[i] = pgi[off]; Bz[i] = pz[off];
        }
        __builtin_amdgcn_sched_barrier(0);  // prefetch issued before compute
        #pragma unroll
        for (int i = 0; i < PFD; ++i)
            step(Age[i], Agi[i], Az[i], t + i);

        #pragma unroll
        for (int i = 0; i < PFD; ++i) {
            int tp = t + 2 * PFD + i; tp = tp < T ? tp : T - 1;
            const size_t off = (size_t)tp * (size_t)N2;
            Age[i] = pge[off]; Agi[i] = pgi[off]; Az[i] = pz[off];
        }
        __builtin_amdgcn_sched_barrier(0);
        #pragma unroll
        for (int i = 0; i < PFD; ++i)
            step(Bge[i], Bgi[i], Bz[i], t + PFD + i);
    }
}

extern "C" void kernel_launch(void* const* d_in, const int* in_sizes, int n_in,
                              void* d_out, int out_size, void* d_ws, size_t ws_size,
                              hipStream_t stream) {
    const float* g_exc   = (const float*)d_in[0];
    const float* g_inh   = (const float*)d_in[1];
    const float* noise   = (const float*)d_in[2];
    const float* v_th    = (const float*)d_in[3];
    const float* tau_ref = (const float*)d_in[4];

    const int N = in_sizes[3];            // 65536
    const int T = in_sizes[0] / N;        // 512

    float* out_spk = (float*)d_out;
    float* out_mem = (float*)d_out + (size_t)T * (size_t)N;

    // Constants computed in double exactly as the Python reference does.
    const double ge_decay = exp(-1.0 / 5.0);
    const double gi_decay = exp(-1.0 / 10.0);
    const double ou_alpha = exp(-1.0 / 5.0);
    const double ou_sigma = 0.02 * sqrt(1.0 - ou_alpha * ou_alpha);

    const int block = 128;                       // 2 waves/block
    const int pairs = N / 2;                     // 32768 threads
    const int grid = (pairs + block - 1) / block;  // 256 blocks = 1/CU
    lif_scan<<<grid, block, 0, stream>>>(
        g_exc, g_inh, noise, v_th, tau_ref, out_spk, out_mem,
        N, T,
        (float)ge_decay, (float)gi_decay, (float)ou_alpha, (float)ou_sigma);
}

// Round 6
// 125.612 us; speedup vs baseline: 1.2884x; 1.2884x over previous
//
#include <hip/hip_runtime.h>
#include <cmath>

// Conductance-based LIF scan: T=512 steps, N=65536 neurons.
// R5: back to R2/R3 grid (1 neuron/lane, 256-thread blocks, 1024 waves ->
// all 4 SIMDs/CU active; R4b showed fewer waves loses). Lever: cut per-step
// VALU count ~73 -> ~30 instrs:
//   - v_rcp_f32 + mul instead of __fdiv_rn (~10 instr correctly-rounded div)
//   - __expf (v_mul + v_exp_f32) instead of ocml expf
//   - allow FMA contraction (drop _rn wrappers)
//   - merged refractory/spike reset (single cndmask)
// Perturbation scale ~1-2 ulp/step — same scale as the validated f64->f32
// exp swap (absmax bit-identical across R1/R3/R4b). gA == 0, elided.

#ifndef PFD
#define PFD 8   // prefetch depth (steps per register block)
#endif

__global__ __launch_bounds__(256, 1) void lif_scan(
    const float* __restrict__ g_exc,
    const float* __restrict__ g_inh,
    const float* __restrict__ noise,
    const float* __restrict__ v_th,
    const float* __restrict__ tau_ref,
    float* __restrict__ out_spk,   // d_out[0 .. T*N)
    float* __restrict__ out_mem,   // d_out[T*N .. 2*T*N)
    int N, int T,
    float cGE, float cGI, float cALPHA, float cSIGMA)
{
    const int n = blockIdx.x * blockDim.x + threadIdx.x;
    if (n >= N) return;

    const float vth = v_th[n];
    const float trf = tau_ref[n];

    float v = 0.0f, gE = 0.0f, gI = 0.0f, ref = 0.0f, ou = 0.0f;

    const float* __restrict__ pge = g_exc + n;
    const float* __restrict__ pgi = g_inh + n;
    const float* __restrict__ pz  = noise + n;

    auto step = [&](float ge_in, float gi_in, float z, int tt) {
        gE = __builtin_fmaf(gE, cGE, ge_in);
        gI = __builtin_fmaf(gI, cGI, gi_in);

        const float gt  = 1.0f + gE + gI;
        const float num = __builtin_fmaf(gI, -0.5f, gE * 3.0f);
        const float vinf = num * __builtin_amdgcn_rcpf(gt);   // ~2 ulp div

        const float decay = __expf(-0.05f * gt);              // mul + v_exp_f32

        v = __builtin_fmaf(v - vinf, decay, vinf);

        ou = __builtin_fmaf(ou, cALPHA, cSIGMA * z);
        v = v + ou;

        const bool in_ref = (ref > 0.0f);
        const bool spike  = (v >= vth) && (!in_ref);   // vth=1>0 so clamp-then-test == this
        v = (in_ref || spike) ? 0.0f : v;
        ref = spike ? trf : fmaxf(ref - 1.0f, 0.0f);

        const size_t off = (size_t)tt * (size_t)N + (size_t)n;
        __builtin_nontemporal_store(spike ? 1.0f : 0.0f, out_spk + off);
        __builtin_nontemporal_store(v, out_mem + off);
    };

    float Age[PFD], Agi[PFD], Az[PFD];
    float Bge[PFD], Bgi[PFD], Bz[PFD];

    // prime buffer A with steps 0..PFD-1
    #pragma unroll
    for (int i = 0; i < PFD; ++i) {
        const size_t off = (size_t)i * (size_t)N;
        Age[i] = pge[off]; Agi[i] = pgi[off]; Az[i] = pz[off];
    }

    // main loop: 2*PFD steps per iteration, ping-pong A/B register blocks
    // (T=512 is an exact multiple of 2*PFD=16; clamp is belt-and-braces)
    for (int t = 0; t < T; t += 2 * PFD) {
        #pragma unroll
        for (int i = 0; i < PFD; ++i) {
            int tp = t + PFD + i; tp = tp < T ? tp : T - 1;
            const size_t off = (size_t)tp * (size_t)N;
            Bge[i] = pge[off]; Bgi[i] = pgi[off]; Bz[i] = pz[off];
        }
        __builtin_amdgcn_sched_barrier(0);  // prefetch issued before compute
        #pragma unroll
        for (int i = 0; i < PFD; ++i)
            step(Age[i], Agi[i], Az[i], t + i);

        #pragma unroll
        for (int i = 0; i < PFD; ++i) {
            int tp = t + 2 * PFD + i; tp = tp < T ? tp : T - 1;
            const size_t off = (size_t)tp * (size_t)N;
            Age[i] = pge[off]; Agi[i] = pgi[off]; Az[i] = pz[off];
        }
        __builtin_amdgcn_sched_barrier(0);
        #pragma unroll
        for (int i = 0; i < PFD; ++i)
            step(Bge[i], Bgi[i], Bz[i], t + PFD + i);
    }
}

extern "C" void kernel_launch(void* const* d_in, const int* in_sizes, int n_in,
                              void* d_out, int out_size, void* d_ws, size_t ws_size,
                              hipStream_t stream) {
    const float* g_exc   = (const float*)d_in[0];
    const float* g_inh   = (const float*)d_in[1];
    const float* noise   = (const float*)d_in[2];
    const float* v_th    = (const float*)d_in[3];
    const float* tau_ref = (const float*)d_in[4];

    const int N = in_sizes[3];            // 65536
    const int T = in_sizes[0] / N;        // 512

    float* out_spk = (float*)d_out;
    float* out_mem = (float*)d_out + (size_t)T * (size_t)N;

    // Constants computed in double exactly as the Python reference does.
    const double ge_decay = exp(-1.0 / 5.0);
    const double gi_decay = exp(-1.0 / 10.0);
    const double ou_alpha = exp(-1.0 / 5.0);
    const double ou_sigma = 0.02 * sqrt(1.0 - ou_alpha * ou_alpha);

    const int block = 256;
    const int grid = (N + block - 1) / block;   // 256 blocks = 1024 waves
    lif_scan<<<grid, block, 0, stream>>>(
        g_exc, g_inh, noise, v_th, tau_ref, out_spk, out_mem,
        N, T,
        (float)ge_decay, (float)gi_decay, (float)ou_alpha, (float)ou_sigma);
}